// Round 1
// baseline (11238.304 us; speedup 1.0000x reference)
//
#include <hip/hip_runtime.h>

typedef float f32x4 __attribute__((ext_vector_type(4)));
typedef __bf16 bf16x8 __attribute__((ext_vector_type(8)));
typedef unsigned short u16x8 __attribute__((ext_vector_type(8)));
typedef unsigned short u16x4 __attribute__((ext_vector_type(4)));

static __device__ __forceinline__ unsigned short f2bf(float f) {
  unsigned int x = __builtin_bit_cast(unsigned int, f);
  x += 0x7FFFu + ((x >> 16) & 1u);
  return (unsigned short)(x >> 16);
}
static __device__ __forceinline__ float bf2f(unsigned short h) {
  unsigned int x = ((unsigned int)h) << 16;
  return __builtin_bit_cast(float, x);
}

// ---------------- f32 -> bf16 elementwise (vectorized) ----------------
__global__ __launch_bounds__(256) void k_f32_to_bf16(
    const float* __restrict__ in, unsigned short* __restrict__ out, int n4) {
  int i = blockIdx.x * 256 + threadIdx.x;
  if (i >= n4) return;
  float4 v = reinterpret_cast<const float4*>(in)[i];
  u16x4 o = {f2bf(v.x), f2bf(v.y), f2bf(v.z), f2bf(v.w)};
  reinterpret_cast<u16x4*>(out)[i] = o;
}

// ---------------- transpose + convert: out[z][n][k] = in[z][k][n] ----------------
// block (32,8), grid (D/32, D/32, nmat)
__global__ __launch_bounds__(256) void k_transpose_bf16(
    const float* __restrict__ in, unsigned short* __restrict__ out, int D) {
  __shared__ float tile[32][33];
  const size_t msz = (size_t)D * D;
  const float* A = in + msz * blockIdx.z;
  unsigned short* O = out + msz * blockIdx.z;
  int nt = blockIdx.x * 32, kt = blockIdx.y * 32;
  int tx = threadIdx.x, ty = threadIdx.y;
#pragma unroll
  for (int i = 0; i < 4; ++i)
    tile[ty + i * 8][tx] = A[(size_t)(kt + ty + i * 8) * D + nt + tx];
  __syncthreads();
#pragma unroll
  for (int i = 0; i < 4; ++i)
    O[(size_t)(nt + ty + i * 8) * D + kt + tx] = f2bf(tile[tx][ty + i * 8]);
}

// ---------------- bf16 GEMM: C[M,N] = A[M,K] @ B^T[N,K], f32 accum ----------------
// 128x128 tile, 4 waves of 64x64 (4x4 fragments of 16x16x32 MFMA), BK=32.
// LDS rows padded to 40 elems (80B) -> 2-way bank aliasing only (free).
// EPI=1: C = relu(acc + C0), used for the self-loop + aggregate + ReLU fusion.
template <int EPI>
__global__ __launch_bounds__(256) void k_gemm_tn(
    const unsigned short* __restrict__ A, const unsigned short* __restrict__ B,
    unsigned short* __restrict__ C, const float* __restrict__ C0,
    int M, int N, int K) {
  __shared__ unsigned short a_lds[128 * 40];
  __shared__ unsigned short b_lds[128 * 40];
  const int tid = threadIdx.x;
  const int lane = tid & 63;
  const int w = tid >> 6;
  const int wr = w >> 1, wc = w & 1;
  const int m0 = blockIdx.y * 128;
  const int n0 = blockIdx.x * 128;
  const int lr = lane & 15, lg = lane >> 4;

  f32x4 acc[4][4] = {};

  for (int k0 = 0; k0 < K; k0 += 32) {
    __syncthreads();
#pragma unroll
    for (int p = 0; p < 2; ++p) {
      int c = p * 256 + tid;
      int row = c >> 2, cc = c & 3;
      int gm = m0 + row;
      u16x8 va = {0, 0, 0, 0, 0, 0, 0, 0};
      if (gm < M)
        va = *reinterpret_cast<const u16x8*>(A + (size_t)gm * K + k0 + cc * 8);
      *reinterpret_cast<u16x8*>(a_lds + row * 40 + cc * 8) = va;
      int gn = n0 + row;  // all N used are multiples of 128 -> always in bounds
      u16x8 vb = *reinterpret_cast<const u16x8*>(B + (size_t)gn * K + k0 + cc * 8);
      *reinterpret_cast<u16x8*>(b_lds + row * 40 + cc * 8) = vb;
    }
    __syncthreads();
    bf16x8 af[4], bfr[4];
#pragma unroll
    for (int i = 0; i < 4; ++i)
      af[i] = *reinterpret_cast<const bf16x8*>(a_lds + (wr * 64 + i * 16 + lr) * 40 + lg * 8);
#pragma unroll
    for (int j = 0; j < 4; ++j)
      bfr[j] = *reinterpret_cast<const bf16x8*>(b_lds + (wc * 64 + j * 16 + lr) * 40 + lg * 8);
#pragma unroll
    for (int i = 0; i < 4; ++i)
#pragma unroll
      for (int j = 0; j < 4; ++j)
        acc[i][j] = __builtin_amdgcn_mfma_f32_16x16x32_bf16(af[i], bfr[j], acc[i][j], 0, 0, 0);
  }

#pragma unroll
  for (int i = 0; i < 4; ++i) {
#pragma unroll
    for (int q = 0; q < 4; ++q) {
      int r = m0 + wr * 64 + i * 16 + lg * 4 + q;
      if (r >= M) continue;
#pragma unroll
      for (int j = 0; j < 4; ++j) {
        int cn = n0 + wc * 64 + j * 16 + lr;
        float v = acc[i][j][q];
        if (EPI) {
          v += C0[(size_t)r * N + cn];
          v = v > 0.f ? v : 0.f;
        }
        C[(size_t)r * N + cn] = f2bf(v);
      }
    }
  }
}

// ---------------- edge message scatter: agg[dst] += norm * HW[src, rel-block] ----------------
// one wave per edge; lane handles 12 contiguous columns (768 = 64*12)
__global__ __launch_bounds__(256) void k_scatter(
    const unsigned short* __restrict__ HW, const int* __restrict__ src,
    const int* __restrict__ dst, const int* __restrict__ rel,
    const float* __restrict__ norm, float* __restrict__ agg,
    int E, int r0, int r1, int ldHW) {
  int e = (blockIdx.x * 256 + threadIdx.x) >> 6;
  if (e >= E) return;
  int r = rel[e];
  if (r < r0 || r >= r1) return;
  int lane = threadIdx.x & 63;
  int s = src[e], d = dst[e];
  float nm = norm[e];
  const unsigned short* row = HW + (size_t)s * ldHW + (size_t)(r - r0) * 768 + lane * 12;
  float* orow = agg + (size_t)d * 768 + lane * 12;
#pragma unroll
  for (int u = 0; u < 3; ++u) {
    u16x4 v = *reinterpret_cast<const u16x4*>(row + u * 4);
#pragma unroll
    for (int j = 0; j < 4; ++j)
      unsafeAtomicAdd(orow + u * 4 + j, nm * bf2f(v[j]));
  }
}

// ---------------- DistMult score: out[t] = dot(SW[es, er-block], emb[eo]) ----------------
__global__ __launch_bounds__(256) void k_score(
    const unsigned short* __restrict__ SW, const unsigned short* __restrict__ emb,
    const int* __restrict__ ps, const int* __restrict__ pr, const int* __restrict__ pd,
    const int* __restrict__ ns, const int* __restrict__ nr, const int* __restrict__ nd,
    float* __restrict__ out, int T, int r0, int r1, int ldSW) {
  int t = (blockIdx.x * 256 + threadIdx.x) >> 6;
  if (t >= 2 * T) return;
  int s, r, o;
  if (t < T) { s = ps[t]; r = pr[t]; o = pd[t]; }
  else       { s = ns[t - T]; r = nr[t - T]; o = nd[t - T]; }
  if (r < r0 || r >= r1) return;
  int lane = threadIdx.x & 63;
  const unsigned short* a = SW + (size_t)s * ldSW + (size_t)(r - r0) * 768 + lane * 12;
  const unsigned short* b = emb + (size_t)o * 768 + lane * 12;
  float acc = 0.f;
#pragma unroll
  for (int u = 0; u < 3; ++u) {
    u16x4 va = *reinterpret_cast<const u16x4*>(a + u * 4);
    u16x4 vb = *reinterpret_cast<const u16x4*>(b + u * 4);
#pragma unroll
    for (int j = 0; j < 4; ++j) acc += bf2f(va[j]) * bf2f(vb[j]);
  }
#pragma unroll
  for (int off = 32; off > 0; off >>= 1) acc += __shfl_down(acc, off, 64);
  if (lane == 0) out[t] = acc;
}

extern "C" void kernel_launch(void* const* d_in, const int* in_sizes, int n_in,
                              void* d_out, int out_size, void* d_ws, size_t ws_size,
                              hipStream_t stream) {
  const float* node_feat = (const float*)d_in[0];
  const float* edge_norm = (const float*)d_in[1];
  const float* W_rel = (const float*)d_in[2];
  const float* W_self = (const float*)d_in[3];
  const float* w_relation = (const float*)d_in[4];
  const int* src = (const int*)d_in[5];
  const int* dst = (const int*)d_in[6];
  const int* rel = (const int*)d_in[7];
  const int* pos_src = (const int*)d_in[8];
  const int* pos_rel = (const int*)d_in[9];
  const int* pos_dst = (const int*)d_in[10];
  const int* neg_src = (const int*)d_in[11];
  const int* neg_rel = (const int*)d_in[12];
  const int* neg_dst = (const int*)d_in[13];

  const int D = 768;
  const int N = in_sizes[0] / D;
  const int E = in_sizes[1];
  const int L = in_sizes[3] / (D * D);
  const int R = in_sizes[4] / (D * D);
  const int T = in_sizes[8];

  auto align_up = [](size_t x) { return (x + 255) & ~(size_t)255; };
  size_t sz_wt_rel = align_up((size_t)L * R * D * D * 2);
  size_t sz_wt_self = align_up((size_t)L * D * D * 2);
  size_t sz_wt_relation = align_up((size_t)R * D * D * 2);
  size_t sz_h = align_up((size_t)N * D * 2);
  size_t sz_agg = align_up((size_t)N * D * 4);
  size_t fixed = sz_wt_rel + sz_wt_self + sz_wt_relation + 2 * sz_h + sz_agg;
  int RG = 8;  // relation group size; shrink until workspace fits
  while (RG > 1 && fixed + (size_t)N * RG * D * 2 > ws_size) RG >>= 1;

  char* wp = (char*)d_ws;
  unsigned short* wt_rel = (unsigned short*)wp; wp += sz_wt_rel;
  unsigned short* wt_self = (unsigned short*)wp; wp += sz_wt_self;
  unsigned short* wt_relation = (unsigned short*)wp; wp += sz_wt_relation;
  unsigned short* h0 = (unsigned short*)wp; wp += sz_h;
  unsigned short* h1 = (unsigned short*)wp; wp += sz_h;
  float* agg = (float*)wp; wp += sz_agg;
  unsigned short* HW = (unsigned short*)wp;

  dim3 tb32(32, 8);
  k_f32_to_bf16<<<(N * D / 4 + 255) / 256, 256, 0, stream>>>(node_feat, h0, N * D / 4);
  k_transpose_bf16<<<dim3(D / 32, D / 32, L * R), tb32, 0, stream>>>(W_rel, wt_rel, D);
  k_transpose_bf16<<<dim3(D / 32, D / 32, L), tb32, 0, stream>>>(W_self, wt_self, D);
  k_transpose_bf16<<<dim3(D / 32, D / 32, R), tb32, 0, stream>>>(w_relation, wt_relation, D);

  const int MT = (N + 127) / 128;
  unsigned short* hcur = h0;
  unsigned short* hnext = h1;
  for (int l = 0; l < L; ++l) {
    hipMemsetAsync(agg, 0, (size_t)N * D * sizeof(float), stream);
    for (int g = 0; g < R; g += RG) {
      int NG = RG * D;
      k_gemm_tn<0><<<dim3(NG / 128, MT), 256, 0, stream>>>(
          hcur, wt_rel + (size_t)(l * R + g) * D * D, HW, nullptr, N, NG, D);
      k_scatter<<<(E + 3) / 4, 256, 0, stream>>>(HW, src, dst, rel, edge_norm,
                                                 agg, E, g, g + RG, NG);
    }
    k_gemm_tn<1><<<dim3(D / 128, MT), 256, 0, stream>>>(
        hcur, wt_self + (size_t)l * D * D, hnext, agg, N, D, D);
    unsigned short* tmp = hcur; hcur = hnext; hnext = tmp;
  }
  // scoring: SW = emb @ w_relation[r] for all r, then per-target dot
  for (int g = 0; g < R; g += RG) {
    int NG = RG * D;
    k_gemm_tn<0><<<dim3(NG / 128, MT), 256, 0, stream>>>(
        hcur, wt_relation + (size_t)g * D * D, HW, nullptr, N, NG, D);
    k_score<<<(2 * T + 3) / 4, 256, 0, stream>>>(HW, hcur, pos_src, pos_rel, pos_dst,
                                                 neg_src, neg_rel, neg_dst,
                                                 (float*)d_out, T, g, g + RG, NG);
  }
}

// Round 2
// 1497.025 us; speedup vs baseline: 7.5071x; 7.5071x over previous
//
#include <hip/hip_runtime.h>

typedef float f32x4 __attribute__((ext_vector_type(4)));
typedef __bf16 bf16x8 __attribute__((ext_vector_type(8)));
typedef unsigned short u16x8 __attribute__((ext_vector_type(8)));
typedef unsigned short u16x4 __attribute__((ext_vector_type(4)));

static __device__ __forceinline__ unsigned short f2bf(float f) {
  unsigned int x = __builtin_bit_cast(unsigned int, f);
  x += 0x7FFFu + ((x >> 16) & 1u);
  return (unsigned short)(x >> 16);
}
static __device__ __forceinline__ float bf2f(unsigned short h) {
  unsigned int x = ((unsigned int)h) << 16;
  return __builtin_bit_cast(float, x);
}

static __device__ __forceinline__ void gload_lds16(const unsigned short* g,
                                                   unsigned short* l) {
  __builtin_amdgcn_global_load_lds(
      (const __attribute__((address_space(1))) void*)g,
      (__attribute__((address_space(3))) void*)l, 16, 0, 0);
}

// ---------------- f32 -> bf16 elementwise (vectorized) ----------------
__global__ __launch_bounds__(256) void k_f32_to_bf16(
    const float* __restrict__ in, unsigned short* __restrict__ out, int n4) {
  int i = blockIdx.x * 256 + threadIdx.x;
  if (i >= n4) return;
  float4 v = reinterpret_cast<const float4*>(in)[i];
  u16x4 o = {f2bf(v.x), f2bf(v.y), f2bf(v.z), f2bf(v.w)};
  reinterpret_cast<u16x4*>(out)[i] = o;
}

// ---------------- transpose + convert: out[z][n][k] = in[z][k][n] ----------------
__global__ __launch_bounds__(256) void k_transpose_bf16(
    const float* __restrict__ in, unsigned short* __restrict__ out, int D) {
  __shared__ float tile[32][33];
  const size_t msz = (size_t)D * D;
  const float* A = in + msz * blockIdx.z;
  unsigned short* O = out + msz * blockIdx.z;
  int nt = blockIdx.x * 32, kt = blockIdx.y * 32;
  int tx = threadIdx.x, ty = threadIdx.y;
#pragma unroll
  for (int i = 0; i < 4; ++i)
    tile[ty + i * 8][tx] = A[(size_t)(kt + ty + i * 8) * D + nt + tx];
  __syncthreads();
#pragma unroll
  for (int i = 0; i < 4; ++i)
    O[(size_t)(nt + ty + i * 8) * D + kt + tx] = f2bf(tile[tx][ty + i * 8]);
}

// ---------------- edge sort by dst: histogram / scan / bucket ----------------
__global__ __launch_bounds__(256) void k_hist(const int* __restrict__ dst,
                                              int* __restrict__ cnt, int E) {
  int e = blockIdx.x * 256 + threadIdx.x;
  if (e < E) atomicAdd(&cnt[dst[e]], 1);
}

// single-wave exclusive scan over N counters (N=20000 -> ~313 iters, ~15 us)
__global__ void k_scan(const int* __restrict__ cnt, int* __restrict__ off, int N) {
  int lane = threadIdx.x;
  int carry = 0;
  for (int base = 0; base < N; base += 64) {
    int i = base + lane;
    int v = (i < N) ? cnt[i] : 0;
    int s = v;
#pragma unroll
    for (int d = 1; d < 64; d <<= 1) {
      int t = __shfl_up(s, d, 64);
      if (lane >= d) s += t;
    }
    if (i < N) off[i] = carry + s - v;
    carry += __shfl(s, 63, 64);
  }
  if (lane == 0) off[N] = carry;
}

__global__ __launch_bounds__(256) void k_bucket(
    const int* __restrict__ src, const int* __restrict__ dst,
    const int* __restrict__ rel, const float* __restrict__ norm,
    const int* __restrict__ off, int* __restrict__ fill,
    int* __restrict__ spack, float* __restrict__ snorm, int E) {
  int e = blockIdx.x * 256 + threadIdx.x;
  if (e >= E) return;
  int d = dst[e];
  int slot = off[d] + atomicAdd(&fill[d], 1);
  spack[slot] = (src[e] << 3) | rel[e];
  snorm[slot] = norm[e];
}

// ---------------- gather-aggregate: agg[v] = sum over in-edges of norm*HW[src,rel] ----------------
// one wave per dst node; lane owns 12 contiguous columns; single plain store (no atomics)
__global__ __launch_bounds__(256) void k_gather(
    const unsigned short* __restrict__ HW, const int* __restrict__ off,
    const int* __restrict__ spack, const float* __restrict__ snorm,
    float* __restrict__ agg, int N, int r0, int r1, int ldHW, int accum) {
  int v = (blockIdx.x * 256 + threadIdx.x) >> 6;
  if (v >= N) return;
  int lane = threadIdx.x & 63;
  int beg = off[v], end = off[v + 1];
  float a[12];
#pragma unroll
  for (int j = 0; j < 12; ++j) a[j] = 0.f;
  for (int p = beg; p < end; ++p) {
    int pk = spack[p];
    float nm = snorm[p];
    int r = pk & 7;
    if (r < r0 || r >= r1) continue;
    const unsigned short* row =
        HW + (size_t)(pk >> 3) * ldHW + (size_t)(r - r0) * 768 + lane * 12;
#pragma unroll
    for (int u = 0; u < 3; ++u) {
      u16x4 vv = *reinterpret_cast<const u16x4*>(row + u * 4);
#pragma unroll
      for (int j = 0; j < 4; ++j) a[u * 4 + j] += nm * bf2f(vv[j]);
    }
  }
  float* orow = agg + (size_t)v * 768 + lane * 12;
  if (accum) {
#pragma unroll
    for (int u = 0; u < 3; ++u) {
      float4 o = reinterpret_cast<float4*>(orow)[u];
      o.x += a[u * 4 + 0]; o.y += a[u * 4 + 1];
      o.z += a[u * 4 + 2]; o.w += a[u * 4 + 3];
      reinterpret_cast<float4*>(orow)[u] = o;
    }
  } else {
#pragma unroll
    for (int u = 0; u < 3; ++u) {
      float4 o = {a[u * 4 + 0], a[u * 4 + 1], a[u * 4 + 2], a[u * 4 + 3]};
      reinterpret_cast<float4*>(orow)[u] = o;
    }
  }
}

// ---------------- bf16 GEMM: C[M,N] = A[M,K] @ B^T[N,K], f32 accum ----------------
// m97 structure: 128x128 tile, BK=32, 4 waves of 64x64, global_load_lds width=16
// into linear LDS [128][32] bf16, with 16B-chunk XOR swizzle (chunk = cs ^ ((row>>1)&3))
// applied on the GLOBAL source and matching XOR on the ds_read -> conflict-free b128 reads.
// A rows must be padded to a multiple of 128 (no per-lane predication on gload_lds).
template <int EPI>
__global__ __launch_bounds__(256) void k_gemm_tn(
    const unsigned short* __restrict__ A, const unsigned short* __restrict__ B,
    unsigned short* __restrict__ C, const float* __restrict__ C0,
    int M, int N, int K) {
  __shared__ unsigned short a_lds[128 * 32];
  __shared__ unsigned short b_lds[128 * 32];
  const int tid = threadIdx.x;
  const int lane = tid & 63;
  const int w = tid >> 6;
  const int wr = w >> 1, wc = w & 1;
  const int m0 = blockIdx.y * 128;
  const int n0 = blockIdx.x * 128;
  const int lr = lane & 15, lg = lane >> 4;

  // staging: wave w, issue q in {0,1} covers rows [w*32+q*16, +16); lane i ->
  // row_local = i>>2, chunk-slot cs = i&3; fetch global chunk cs^((row>>1)&3)
  const int srow = w * 32 + (lane >> 2);
  const int cs = lane & 3;
  const int gc0 = (cs ^ ((srow >> 1) & 3)) * 8;
  const int gc1 = (cs ^ (((srow + 16) >> 1) & 3)) * 8;
  const unsigned short* pa0 = A + (size_t)(m0 + srow) * K + gc0;
  const unsigned short* pa1 = A + (size_t)(m0 + srow + 16) * K + gc1;
  const unsigned short* pb0 = B + (size_t)(n0 + srow) * K + gc0;
  const unsigned short* pb1 = B + (size_t)(n0 + srow + 16) * K + gc1;
  unsigned short* la = a_lds + w * 1024;  // (w*2)*512 ushorts
  unsigned short* lb = b_lds + w * 1024;

  // read-side chunk xor: (row>>1)&3 == (lr>>1)&3 since wr*64+i*16 is mult of 16
  const int ro = (lg ^ ((lr >> 1) & 3)) * 8;

  f32x4 acc[4][4] = {};

  for (int k0 = 0; k0 < K; k0 += 32) {
    __syncthreads();
    gload_lds16(pa0 + k0, la);
    gload_lds16(pa1 + k0, la + 512);
    gload_lds16(pb0 + k0, lb);
    gload_lds16(pb1 + k0, lb + 512);
    __syncthreads();  // compiler drains vmcnt(0) before barrier -> tiles ready
    bf16x8 af[4], bfv[4];
#pragma unroll
    for (int i = 0; i < 4; ++i)
      af[i] = *reinterpret_cast<const bf16x8*>(a_lds + (wr * 64 + i * 16 + lr) * 32 + ro);
#pragma unroll
    for (int j = 0; j < 4; ++j)
      bfv[j] = *reinterpret_cast<const bf16x8*>(b_lds + (wc * 64 + j * 16 + lr) * 32 + ro);
#pragma unroll
    for (int i = 0; i < 4; ++i)
#pragma unroll
      for (int j = 0; j < 4; ++j)
        acc[i][j] = __builtin_amdgcn_mfma_f32_16x16x32_bf16(af[i], bfv[j], acc[i][j], 0, 0, 0);
  }

#pragma unroll
  for (int i = 0; i < 4; ++i) {
#pragma unroll
    for (int q = 0; q < 4; ++q) {
      int r = m0 + wr * 64 + i * 16 + lg * 4 + q;
      if (r >= M) continue;
#pragma unroll
      for (int j = 0; j < 4; ++j) {
        int cn = n0 + wc * 64 + j * 16 + lr;
        float v = acc[i][j][q];
        if (EPI) {
          v += C0[(size_t)r * N + cn];
          v = v > 0.f ? v : 0.f;
        }
        C[(size_t)r * N + cn] = f2bf(v);
      }
    }
  }
}

// ---------------- DistMult score: out[t] = dot(SW[es, er], emb[eo]) ----------------
__global__ __launch_bounds__(256) void k_score(
    const unsigned short* __restrict__ SW, const unsigned short* __restrict__ emb,
    const int* __restrict__ ps, const int* __restrict__ pr, const int* __restrict__ pd,
    const int* __restrict__ ns, const int* __restrict__ nr, const int* __restrict__ nd,
    float* __restrict__ out, int T, int r0, int r1, int ldSW) {
  int t = (blockIdx.x * 256 + threadIdx.x) >> 6;
  if (t >= 2 * T) return;
  int s, r, o;
  if (t < T) { s = ps[t]; r = pr[t]; o = pd[t]; }
  else       { s = ns[t - T]; r = nr[t - T]; o = nd[t - T]; }
  if (r < r0 || r >= r1) return;
  int lane = threadIdx.x & 63;
  const unsigned short* a = SW + (size_t)s * ldSW + (size_t)(r - r0) * 768 + lane * 12;
  const unsigned short* b = emb + (size_t)o * 768 + lane * 12;
  float acc = 0.f;
#pragma unroll
  for (int u = 0; u < 3; ++u) {
    u16x4 va = *reinterpret_cast<const u16x4*>(a + u * 4);
    u16x4 vb = *reinterpret_cast<const u16x4*>(b + u * 4);
#pragma unroll
    for (int j = 0; j < 4; ++j) acc += bf2f(va[j]) * bf2f(vb[j]);
  }
#pragma unroll
  for (int off = 32; off > 0; off >>= 1) acc += __shfl_down(acc, off, 64);
  if (lane == 0) out[t] = acc;
}

extern "C" void kernel_launch(void* const* d_in, const int* in_sizes, int n_in,
                              void* d_out, int out_size, void* d_ws, size_t ws_size,
                              hipStream_t stream) {
  const float* node_feat = (const float*)d_in[0];
  const float* edge_norm = (const float*)d_in[1];
  const float* W_rel = (const float*)d_in[2];
  const float* W_self = (const float*)d_in[3];
  const float* w_relation = (const float*)d_in[4];
  const int* src = (const int*)d_in[5];
  const int* dst = (const int*)d_in[6];
  const int* rel = (const int*)d_in[7];
  const int* pos_src = (const int*)d_in[8];
  const int* pos_rel = (const int*)d_in[9];
  const int* pos_dst = (const int*)d_in[10];
  const int* neg_src = (const int*)d_in[11];
  const int* neg_rel = (const int*)d_in[12];
  const int* neg_dst = (const int*)d_in[13];

  const int D = 768;
  const int N = in_sizes[0] / D;
  const int E = in_sizes[1];
  const int L = in_sizes[3] / (D * D);
  const int R = in_sizes[4] / (D * D);
  const int T = in_sizes[8];
  const int Mpad = (N + 127) & ~127;  // A-rows padded: gload_lds has no predication

  auto align_up = [](size_t x) { return (x + 255) & ~(size_t)255; };
  size_t sz_wt_rel = align_up((size_t)L * R * D * D * 2);
  size_t sz_wt_self = align_up((size_t)L * D * D * 2);
  size_t sz_wt_relation = align_up((size_t)R * D * D * 2);
  size_t sz_h = align_up((size_t)Mpad * D * 2);
  size_t sz_agg = align_up((size_t)N * D * 4);
  size_t sz_cntfill = align_up((size_t)2 * N * 4);
  size_t sz_off = align_up((size_t)(N + 8) * 4);
  size_t sz_spack = align_up((size_t)E * 4);
  size_t sz_snorm = align_up((size_t)E * 4);
  size_t fixed = sz_wt_rel + sz_wt_self + sz_wt_relation + 2 * sz_h + sz_agg +
                 sz_cntfill + sz_off + sz_spack + sz_snorm;
  int RG = 8;
  while (RG > 1 && fixed + (size_t)N * RG * D * 2 > ws_size) RG >>= 1;

  char* wp = (char*)d_ws;
  unsigned short* wt_rel = (unsigned short*)wp; wp += sz_wt_rel;
  unsigned short* wt_self = (unsigned short*)wp; wp += sz_wt_self;
  unsigned short* wt_relation = (unsigned short*)wp; wp += sz_wt_relation;
  unsigned short* h0 = (unsigned short*)wp; wp += sz_h;
  unsigned short* h1 = (unsigned short*)wp; wp += sz_h;
  float* agg = (float*)wp; wp += sz_agg;
  int* cnt = (int*)wp; int* fill = cnt + N; wp += sz_cntfill;
  int* off = (int*)wp; wp += sz_off;
  int* spack = (int*)wp; wp += sz_spack;
  float* snorm = (float*)wp; wp += sz_snorm;
  unsigned short* HW = (unsigned short*)wp;

  dim3 tb32(32, 8);
  k_f32_to_bf16<<<(N * D / 4 + 255) / 256, 256, 0, stream>>>(node_feat, h0, N * D / 4);
  k_transpose_bf16<<<dim3(D / 32, D / 32, L * R), tb32, 0, stream>>>(W_rel, wt_rel, D);
  k_transpose_bf16<<<dim3(D / 32, D / 32, L), tb32, 0, stream>>>(W_self, wt_self, D);
  k_transpose_bf16<<<dim3(D / 32, D / 32, R), tb32, 0, stream>>>(w_relation, wt_relation, D);

  // counting sort of edges by dst (call-invariant; once per launch)
  hipMemsetAsync(cnt, 0, (size_t)2 * N * 4, stream);
  k_hist<<<(E + 255) / 256, 256, 0, stream>>>(dst, cnt, E);
  k_scan<<<1, 64, 0, stream>>>(cnt, off, N);
  k_bucket<<<(E + 255) / 256, 256, 0, stream>>>(src, dst, rel, edge_norm, off, fill,
                                                spack, snorm, E);

  const int MT = Mpad / 128;
  unsigned short* hcur = h0;
  unsigned short* hnext = h1;
  for (int l = 0; l < L; ++l) {
    for (int g = 0; g < R; g += RG) {
      int NG = RG * D;
      k_gemm_tn<0><<<dim3(NG / 128, MT), 256, 0, stream>>>(
          hcur, wt_rel + (size_t)(l * R + g) * D * D, HW, nullptr, N, NG, D);
      k_gather<<<(N + 3) / 4, 256, 0, stream>>>(HW, off, spack, snorm, agg, N,
                                                g, g + RG, NG, g > 0 ? 1 : 0);
    }
    k_gemm_tn<1><<<dim3(D / 128, MT), 256, 0, stream>>>(
        hcur, wt_self + (size_t)l * D * D, hnext, agg, N, D, D);
    unsigned short* tmp = hcur; hcur = hnext; hnext = tmp;
  }
  // scoring: SW = emb @ w_relation[r] for all r, then per-target dot
  for (int g = 0; g < R; g += RG) {
    int NG = RG * D;
    k_gemm_tn<0><<<dim3(NG / 128, MT), 256, 0, stream>>>(
        hcur, wt_relation + (size_t)g * D * D, HW, nullptr, N, NG, D);
    k_score<<<(2 * T + 3) / 4, 256, 0, stream>>>(HW, hcur, pos_src, pos_rel, pos_dst,
                                                 neg_src, neg_rel, neg_dst,
                                                 (float*)d_out, T, g, g + RG, NG);
  }
}

// Round 3
// 1271.917 us; speedup vs baseline: 8.8357x; 1.1770x over previous
//
#include <hip/hip_runtime.h>

typedef float f32x4 __attribute__((ext_vector_type(4)));
typedef __bf16 bf16x8 __attribute__((ext_vector_type(8)));
typedef unsigned short u16x8 __attribute__((ext_vector_type(8)));
typedef unsigned short u16x4 __attribute__((ext_vector_type(4)));

static __device__ __forceinline__ unsigned short f2bf(float f) {
  unsigned int x = __builtin_bit_cast(unsigned int, f);
  x += 0x7FFFu + ((x >> 16) & 1u);
  return (unsigned short)(x >> 16);
}
static __device__ __forceinline__ float bf2f(unsigned short h) {
  unsigned int x = ((unsigned int)h) << 16;
  return __builtin_bit_cast(float, x);
}

static __device__ __forceinline__ void gload_lds16(const unsigned short* g,
                                                   unsigned short* l) {
  __builtin_amdgcn_global_load_lds(
      (const __attribute__((address_space(1))) void*)g,
      (__attribute__((address_space(3))) void*)l, 16, 0, 0);
}

// ---------------- f32 -> bf16 elementwise (vectorized) ----------------
__global__ __launch_bounds__(256) void k_f32_to_bf16(
    const float* __restrict__ in, unsigned short* __restrict__ out, int n4) {
  int i = blockIdx.x * 256 + threadIdx.x;
  if (i >= n4) return;
  float4 v = reinterpret_cast<const float4*>(in)[i];
  u16x4 o = {f2bf(v.x), f2bf(v.y), f2bf(v.z), f2bf(v.w)};
  reinterpret_cast<u16x4*>(out)[i] = o;
}

// ---------------- transpose + convert: out[z][n][k] = in[z][k][n] ----------------
__global__ __launch_bounds__(256) void k_transpose_bf16(
    const float* __restrict__ in, unsigned short* __restrict__ out, int D) {
  __shared__ float tile[32][33];
  const size_t msz = (size_t)D * D;
  const float* A = in + msz * blockIdx.z;
  unsigned short* O = out + msz * blockIdx.z;
  int nt = blockIdx.x * 32, kt = blockIdx.y * 32;
  int tx = threadIdx.x, ty = threadIdx.y;
#pragma unroll
  for (int i = 0; i < 4; ++i)
    tile[ty + i * 8][tx] = A[(size_t)(kt + ty + i * 8) * D + nt + tx];
  __syncthreads();
#pragma unroll
  for (int i = 0; i < 4; ++i)
    O[(size_t)(nt + ty + i * 8) * D + kt + tx] = f2bf(tile[tx][ty + i * 8]);
}

// ---------------- edge sort by dst: histogram / scan / bucket ----------------
__global__ __launch_bounds__(256) void k_hist(const int* __restrict__ dst,
                                              int* __restrict__ cnt, int E) {
  int e = blockIdx.x * 256 + threadIdx.x;
  if (e < E) atomicAdd(&cnt[dst[e]], 1);
}

// block-parallel exclusive scan (1 block x 1024 threads, chunk per thread)
__global__ __launch_bounds__(1024) void k_scan(const int* __restrict__ cnt,
                                               int* __restrict__ off, int N) {
  __shared__ int wpre[16];
  int tid = threadIdx.x, lane = tid & 63, w = tid >> 6;
  const int CH = (N + 1023) >> 10;
  int base = tid * CH;
  int s = 0;
  for (int j = 0; j < CH; ++j) {
    int i = base + j;
    s += (i < N) ? cnt[i] : 0;
  }
  int inc = s;
#pragma unroll
  for (int d = 1; d < 64; d <<= 1) {
    int t2 = __shfl_up(inc, d, 64);
    if (lane >= d) inc += t2;
  }
  if (lane == 63) wpre[w] = inc;
  __syncthreads();
  if (w == 0) {
    int v = (lane < 16) ? wpre[lane] : 0;
    int p = v;
#pragma unroll
    for (int d = 1; d < 16; d <<= 1) {
      int t2 = __shfl_up(p, d, 64);
      if (lane >= d) p += t2;
    }
    if (lane < 16) wpre[lane] = p - v;  // exclusive wave base
  }
  __syncthreads();
  int run = wpre[w] + inc - s;  // exclusive prefix for this thread's chunk
  for (int j = 0; j < CH; ++j) {
    int i = base + j;
    if (i < N) {
      off[i] = run;
      run += cnt[i];
    }
  }
  if (tid == 1023) off[N] = run;
}

__global__ __launch_bounds__(256) void k_bucket(
    const int* __restrict__ src, const int* __restrict__ dst,
    const int* __restrict__ rel, const float* __restrict__ norm,
    const int* __restrict__ off, int* __restrict__ fill,
    int* __restrict__ spack, float* __restrict__ snorm, int E) {
  int e = blockIdx.x * 256 + threadIdx.x;
  if (e >= E) return;
  int d = dst[e];
  int slot = off[d] + atomicAdd(&fill[d], 1);
  spack[slot] = (src[e] << 3) | rel[e];
  snorm[slot] = norm[e];
}

// ---------------- gather-aggregate: agg[v] = sum over in-edges of norm*HW[src,rel] ----------------
__global__ __launch_bounds__(256) void k_gather(
    const unsigned short* __restrict__ HW, const int* __restrict__ off,
    const int* __restrict__ spack, const float* __restrict__ snorm,
    float* __restrict__ agg, int N, int r0, int r1, int ldHW, int accum) {
  int v = (blockIdx.x * 256 + threadIdx.x) >> 6;
  if (v >= N) return;
  int lane = threadIdx.x & 63;
  int beg = off[v], end = off[v + 1];
  float a[12];
#pragma unroll
  for (int j = 0; j < 12; ++j) a[j] = 0.f;
  for (int p = beg; p < end; ++p) {
    int pk = spack[p];
    float nm = snorm[p];
    int r = pk & 7;
    if (r < r0 || r >= r1) continue;
    const unsigned short* row =
        HW + (size_t)(pk >> 3) * ldHW + (size_t)(r - r0) * 768 + lane * 12;
#pragma unroll
    for (int u = 0; u < 3; ++u) {
      u16x4 vv = *reinterpret_cast<const u16x4*>(row + u * 4);
#pragma unroll
      for (int j = 0; j < 4; ++j) a[u * 4 + j] += nm * bf2f(vv[j]);
    }
  }
  float* orow = agg + (size_t)v * 768 + lane * 12;
  if (accum) {
#pragma unroll
    for (int u = 0; u < 3; ++u) {
      float4 o = reinterpret_cast<float4*>(orow)[u];
      o.x += a[u * 4 + 0]; o.y += a[u * 4 + 1];
      o.z += a[u * 4 + 2]; o.w += a[u * 4 + 3];
      reinterpret_cast<float4*>(orow)[u] = o;
    }
  } else {
#pragma unroll
    for (int u = 0; u < 3; ++u) {
      float4 o = {a[u * 4 + 0], a[u * 4 + 1], a[u * 4 + 2], a[u * 4 + 3]};
      reinterpret_cast<float4*>(orow)[u] = o;
    }
  }
}

// ---------------- bf16 GEMM: C[M,N] = A[M,K] @ B^T[N,K], f32 accum ----------------
// 256x256 tile, BK=32, 8 waves (2Mx4N, 128x64 each), depth-3 LDS rotation:
// iter t reads buf[t%3]; tile t+2 streams into buf[(t+2)%3] via global_load_lds
// width=16 (pre-swizzled global source, XOR chunk swizzle, matching ds_read XOR
// -> 2-way bank alias only = free). One raw s_barrier + counted vmcnt(4) per
// K-tile; never drains to 0 until the last tile (T4). setprio around MFMA (T5).
// A rows and B rows must be padded to multiples of 256 (no gload_lds predication).
template <int EPI>
__global__ __launch_bounds__(512, 2) void k_gemm_tn(
    const unsigned short* __restrict__ A, const unsigned short* __restrict__ B,
    unsigned short* __restrict__ C, const float* __restrict__ C0,
    int M, int N, int K, int MT, int NT) {
  __shared__ unsigned short As[3][8192];
  __shared__ unsigned short Bs[3][8192];
  const int tid = threadIdx.x;
  const int lane = tid & 63;
  const int w = tid >> 6;  // 0..7
  const int wr = w >> 2;   // M half
  const int wc = w & 3;    // N quarter

  // supergroup-of-8 M-tiles block swizzle for B-panel L2 reuse
  int bid = blockIdx.x;
  const int per = 8 * NT;
  int grp = bid / per, rem = bid % per;
  int mstart = grp * 8;
  int gsz = MT - mstart; if (gsz > 8) gsz = 8;
  const int mt = mstart + rem % gsz;
  const int ntile = rem / gsz;
  const int m0 = mt * 256, n0 = ntile * 256;

  const int lr = lane & 15, lg = lane >> 4;
  const int ro = (lg ^ ((lr >> 1) & 3)) * 8;  // read-side chunk XOR

  // staging: thread covers rows (tid>>2) and (tid>>2)+128, chunk slot tid&3;
  // fetch global chunk (tid&3) ^ ((row>>1)&3)  [row>>1 == tid>>3 mod 4]
  const int srow = tid >> 2;
  const int gchunk = ((tid & 3) ^ ((tid >> 3) & 3)) * 8;
  const unsigned short* pa0 = A + (size_t)(m0 + srow) * K + gchunk;
  const unsigned short* pa1 = A + (size_t)(m0 + srow + 128) * K + gchunk;
  const unsigned short* pb0 = B + (size_t)(n0 + srow) * K + gchunk;
  const unsigned short* pb1 = B + (size_t)(n0 + srow + 128) * K + gchunk;
  const int wlds = w * 512;  // wave-uniform stage dest (ushort offset)

  f32x4 acc[8][4] = {};
  const int nk = K >> 5;

  // prologue: tile 0 -> buf0, tile 1 -> buf1
  gload_lds16(pa0, &As[0][wlds]);
  gload_lds16(pa1, &As[0][4096 + wlds]);
  gload_lds16(pb0, &Bs[0][wlds]);
  gload_lds16(pb1, &Bs[0][4096 + wlds]);
  gload_lds16(pa0 + 32, &As[1][wlds]);
  gload_lds16(pa1 + 32, &As[1][4096 + wlds]);
  gload_lds16(pb0 + 32, &Bs[1][wlds]);
  gload_lds16(pb1 + 32, &Bs[1][4096 + wlds]);

  int buf = 0;
  for (int t = 0; t < nk; ++t) {
    // my tile-t loads done (4 newest = tile t+1 may stay in flight)
    if (t + 1 < nk) {
      asm volatile("s_waitcnt vmcnt(4)" ::: "memory");
    } else {
      asm volatile("s_waitcnt vmcnt(0)" ::: "memory");
    }
    __builtin_amdgcn_s_barrier();  // -> ALL waves' tile-t loads done
    asm volatile("" ::: "memory");
    if (t + 2 < nk) {
      int b2 = buf >= 1 ? buf - 1 : 2;  // (buf+2)%3
      int ko = (t + 2) << 5;
      gload_lds16(pa0 + ko, &As[b2][wlds]);
      gload_lds16(pa1 + ko, &As[b2][4096 + wlds]);
      gload_lds16(pb0 + ko, &Bs[b2][wlds]);
      gload_lds16(pb1 + ko, &Bs[b2][4096 + wlds]);
    }
    const unsigned short* abase = &As[buf][(wr * 128 + lr) * 32 + ro];
    const unsigned short* bbase = &Bs[buf][(wc * 64 + lr) * 32 + ro];
    bf16x8 bfv[4], af[4];
#pragma unroll
    for (int j = 0; j < 4; ++j)
      bfv[j] = *reinterpret_cast<const bf16x8*>(bbase + j * 16 * 32);
#pragma unroll
    for (int i = 0; i < 4; ++i)
      af[i] = *reinterpret_cast<const bf16x8*>(abase + i * 16 * 32);
    __builtin_amdgcn_s_setprio(1);
#pragma unroll
    for (int i = 0; i < 4; ++i)
#pragma unroll
      for (int j = 0; j < 4; ++j)
        acc[i][j] = __builtin_amdgcn_mfma_f32_16x16x32_bf16(af[i], bfv[j], acc[i][j], 0, 0, 0);
    __builtin_amdgcn_s_setprio(0);
#pragma unroll
    for (int i = 0; i < 4; ++i)
      af[i] = *reinterpret_cast<const bf16x8*>(abase + (64 + i * 16) * 32);
    __builtin_amdgcn_s_setprio(1);
#pragma unroll
    for (int i = 0; i < 4; ++i)
#pragma unroll
      for (int j = 0; j < 4; ++j)
        acc[4 + i][j] = __builtin_amdgcn_mfma_f32_16x16x32_bf16(af[i], bfv[j], acc[4 + i][j], 0, 0, 0);
    __builtin_amdgcn_s_setprio(0);
    buf = buf == 2 ? 0 : buf + 1;
  }

#pragma unroll
  for (int i = 0; i < 8; ++i) {
#pragma unroll
    for (int q = 0; q < 4; ++q) {
      int r = m0 + wr * 128 + i * 16 + lg * 4 + q;
      if (r >= M) continue;
#pragma unroll
      for (int j = 0; j < 4; ++j) {
        int cn = n0 + wc * 64 + j * 16 + lr;
        float v = acc[i][j][q];
        if (EPI) {
          v += C0[(size_t)r * N + cn];
          v = v > 0.f ? v : 0.f;
        }
        C[(size_t)r * N + cn] = f2bf(v);
      }
    }
  }
}

// ---------------- DistMult score: out[t] = dot(SW[es, er], emb[eo]) ----------------
__global__ __launch_bounds__(256) void k_score(
    const unsigned short* __restrict__ SW, const unsigned short* __restrict__ emb,
    const int* __restrict__ ps, const int* __restrict__ pr, const int* __restrict__ pd,
    const int* __restrict__ ns, const int* __restrict__ nr, const int* __restrict__ nd,
    float* __restrict__ out, int T, int r0, int r1, int ldSW) {
  int t = (blockIdx.x * 256 + threadIdx.x) >> 6;
  if (t >= 2 * T) return;
  int s, r, o;
  if (t < T) { s = ps[t]; r = pr[t]; o = pd[t]; }
  else       { s = ns[t - T]; r = nr[t - T]; o = nd[t - T]; }
  if (r < r0 || r >= r1) return;
  int lane = threadIdx.x & 63;
  const unsigned short* a = SW + (size_t)s * ldSW + (size_t)(r - r0) * 768 + lane * 12;
  const unsigned short* b = emb + (size_t)o * 768 + lane * 12;
  float acc = 0.f;
#pragma unroll
  for (int u = 0; u < 3; ++u) {
    u16x4 va = *reinterpret_cast<const u16x4*>(a + u * 4);
    u16x4 vb = *reinterpret_cast<const u16x4*>(b + u * 4);
#pragma unroll
    for (int j = 0; j < 4; ++j) acc += bf2f(va[j]) * bf2f(vb[j]);
  }
#pragma unroll
  for (int off = 32; off > 0; off >>= 1) acc += __shfl_down(acc, off, 64);
  if (lane == 0) out[t] = acc;
}

extern "C" void kernel_launch(void* const* d_in, const int* in_sizes, int n_in,
                              void* d_out, int out_size, void* d_ws, size_t ws_size,
                              hipStream_t stream) {
  const float* node_feat = (const float*)d_in[0];
  const float* edge_norm = (const float*)d_in[1];
  const float* W_rel = (const float*)d_in[2];
  const float* W_self = (const float*)d_in[3];
  const float* w_relation = (const float*)d_in[4];
  const int* src = (const int*)d_in[5];
  const int* dst = (const int*)d_in[6];
  const int* rel = (const int*)d_in[7];
  const int* pos_src = (const int*)d_in[8];
  const int* pos_rel = (const int*)d_in[9];
  const int* pos_dst = (const int*)d_in[10];
  const int* neg_src = (const int*)d_in[11];
  const int* neg_rel = (const int*)d_in[12];
  const int* neg_dst = (const int*)d_in[13];

  const int D = 768;
  const int N = in_sizes[0] / D;
  const int E = in_sizes[1];
  const int L = in_sizes[3] / (D * D);
  const int R = in_sizes[4] / (D * D);
  const int T = in_sizes[8];
  const int Mpad = (N + 255) & ~255;  // 256-row tiles, no gload_lds predication

  auto align_up = [](size_t x) { return (x + 255) & ~(size_t)255; };
  size_t sz_wt_rel = align_up((size_t)L * R * D * D * 2);
  size_t sz_wt_self = align_up((size_t)L * D * D * 2);
  size_t sz_wt_relation = align_up((size_t)R * D * D * 2);
  size_t sz_h = align_up((size_t)Mpad * D * 2);
  size_t sz_agg = align_up((size_t)N * D * 4);
  size_t sz_cntfill = align_up((size_t)2 * N * 4);
  size_t sz_off = align_up((size_t)(N + 8) * 4);
  size_t sz_spack = align_up((size_t)E * 4);
  size_t sz_snorm = align_up((size_t)E * 4);
  size_t fixed = sz_wt_rel + sz_wt_self + sz_wt_relation + 2 * sz_h + sz_agg +
                 sz_cntfill + sz_off + sz_spack + sz_snorm;
  int RG = 8;
  while (RG > 1 && fixed + (size_t)Mpad * RG * D * 2 > ws_size) RG >>= 1;

  char* wp = (char*)d_ws;
  unsigned short* wt_rel = (unsigned short*)wp; wp += sz_wt_rel;
  unsigned short* wt_self = (unsigned short*)wp; wp += sz_wt_self;
  unsigned short* wt_relation = (unsigned short*)wp; wp += sz_wt_relation;
  unsigned short* h0 = (unsigned short*)wp; wp += sz_h;
  unsigned short* h1 = (unsigned short*)wp; wp += sz_h;
  float* agg = (float*)wp; wp += sz_agg;
  int* cnt = (int*)wp; int* fill = cnt + N; wp += sz_cntfill;
  int* off = (int*)wp; wp += sz_off;
  int* spack = (int*)wp; wp += sz_spack;
  float* snorm = (float*)wp; wp += sz_snorm;
  unsigned short* HW = (unsigned short*)wp;

  dim3 tb32(32, 8);
  k_f32_to_bf16<<<(N * D / 4 + 255) / 256, 256, 0, stream>>>(node_feat, h0, N * D / 4);
  k_transpose_bf16<<<dim3(D / 32, D / 32, L * R), tb32, 0, stream>>>(W_rel, wt_rel, D);
  k_transpose_bf16<<<dim3(D / 32, D / 32, L), tb32, 0, stream>>>(W_self, wt_self, D);
  k_transpose_bf16<<<dim3(D / 32, D / 32, R), tb32, 0, stream>>>(w_relation, wt_relation, D);

  // counting sort of edges by dst
  hipMemsetAsync(cnt, 0, (size_t)2 * N * 4, stream);
  k_hist<<<(E + 255) / 256, 256, 0, stream>>>(dst, cnt, E);
  k_scan<<<1, 1024, 0, stream>>>(cnt, off, N);
  k_bucket<<<(E + 255) / 256, 256, 0, stream>>>(src, dst, rel, edge_norm, off, fill,
                                                spack, snorm, E);

  const int MT = Mpad / 256;
  unsigned short* hcur = h0;
  unsigned short* hnext = h1;
  for (int l = 0; l < L; ++l) {
    for (int g = 0; g < R; g += RG) {
      int NG = RG * D;
      int NT = NG / 256;
      k_gemm_tn<0><<<MT * NT, 512, 0, stream>>>(
          hcur, wt_rel + (size_t)(l * R + g) * D * D, HW, nullptr, N, NG, D, MT, NT);
      k_gather<<<(N + 3) / 4, 256, 0, stream>>>(HW, off, spack, snorm, agg, N,
                                                g, g + RG, NG, g > 0 ? 1 : 0);
    }
    {
      int NT = D / 256;
      k_gemm_tn<1><<<MT * NT, 512, 0, stream>>>(
          hcur, wt_self + (size_t)l * D * D, hnext, agg, N, D, D, MT, NT);
    }
    unsigned short* tmp = hcur; hcur = hnext; hnext = tmp;
  }
  // scoring: SW = emb @ w_relation[r] for all r, then per-target dot
  for (int g = 0; g < R; g += RG) {
    int NG = RG * D;
    int NT = NG / 256;
    k_gemm_tn<0><<<MT * NT, 512, 0, stream>>>(
        hcur, wt_relation + (size_t)g * D * D, HW, nullptr, N, NG, D, MT, NT);
    k_score<<<(2 * T + 3) / 4, 256, 0, stream>>>(HW, hcur, pos_src, pos_rel, pos_dst,
                                                 neg_src, neg_rel, neg_dst,
                                                 (float*)d_out, T, g, g + RG, NG);
  }
}